// Round 1
// 686.078 us; speedup vs baseline: 1.1797x; 1.1797x over previous
//
#include <hip/hip_runtime.h>
#include <math.h>

#define N   4096
#define NO  4097   // output spatial dim (4096 + 4pad - 4 + 1)
#define TO  32     // output tile
#define GW  129    // grid width = ceil(NO/TO)

struct OrientCoef { float c[8]; float s[8]; };

// LDS 40,880 B -> rounds to 40,960 -> exactly 4 blocks/CU (16 waves/CU).
__global__ __launch_bounds__(256, 4) void sift_fused(const float* __restrict__ x,
                                                     float* __restrict__ out,
                                                     OrientCoef cf) {
    // ---- bijective XCD-aware swizzle: consecutive tiles -> same XCD L2 ----
    int bid = blockIdx.y * GW + blockIdx.x;
    {
        const int nwg = GW * GW;             // 16641
        const int q = nwg / 8, r = nwg % 8;  // 2080, 1
        int xcd = bid & 7, local = bid >> 3;
        bid = (xcd < r ? xcd * (q + 1) : r * (q + 1) + (xcd - r) * q) + local;
    }
    const int i0  = (bid / GW) * TO;
    const int j0  = (bid % GW) * TO;
    const int tid = threadIdx.x;

    // LDS layout:
    //   [0, 5040)        packed (mag|idx) [35][36] f32
    //   [5040, 40880)    hsum [8][35][32] f32; xs [37][38] f32 overlaid (dead by phase 3)
    __shared__ __align__(16) char smem[5040 + 8 * 35 * 32 * 4];
    float (*packed)[36]   = reinterpret_cast<float(*)[36]>(smem);
    float (*hsum)[35][32] = reinterpret_cast<float(*)[35][32]>(smem + 5040);
    float (*xs)[38]       = reinterpret_cast<float(*)[38]>(smem + 5040);

    // ---- phase 1: stage x halo (zero-padded) ----
    for (int l = tid; l < 37 * 37; l += 256) {
        int lr = l / 37, lc = l % 37;
        int gr = i0 - 3 + lr, gc = j0 - 3 + lc;
        float v = 0.0f;
        if (gr >= 0 && gr < N && gc >= 0 && gc < N) v = x[(size_t)gr * N + gc];
        xs[lr][lc] = v;
    }
    __syncthreads();

    // ---- phase 2: Sobel + magnitude + orientation argmax, pack (mag|idx) ----
    for (int l = tid; l < 35 * 35; l += 256) {
        int lr = l / 35, lc = l % 35;
        int gr = i0 - 2 + lr, gc = j0 - 2 + lc;
        float pv = 0.0f;
        if (gr >= 0 && gr < N && gc >= 0 && gc < N) {
            float x00 = xs[lr][lc],     x01 = xs[lr][lc + 1],     x02 = xs[lr][lc + 2];
            float x10 = xs[lr + 1][lc],                           x12 = xs[lr + 1][lc + 2];
            float x20 = xs[lr + 2][lc], x21 = xs[lr + 2][lc + 1], x22 = xs[lr + 2][lc + 2];
            // unflipped sobel taps (lax conv = cross-correlation)
            float dx = (x02 - x00) + 2.0f * (x12 - x10) + (x22 - x20);
            float dy = (x20 - x00) + 2.0f * (x21 - x01) + (x22 - x02);
            float mag = sqrtf(dx * dx + dy * dy);
            // per-bin coefficients (reference rounds each f32 angle separately)
            int best = 0;
            float bv = fmaf(cf.s[0], dy, cf.c[0] * dx);
            #pragma unroll
            for (int o = 1; o < 8; ++o) {
                float cs = fmaf(cf.s[o], dy, cf.c[o] * dx);
                if (cs > bv) { bv = cs; best = o; }
            }
            // pack idx into low 3 mantissa bits (<= 8e-7 relative mag error)
            pv = __uint_as_float((__float_as_uint(mag) & ~7u) | (unsigned)best);
        }
        packed[lr][lc] = pv;
    }
    __syncthreads();   // last xs read above; hsum overwrites xs region below

    // ---- phase 3: horizontal 4-window per-channel sums in REGISTERS ----
    for (int l = tid; l < 35 * 32; l += 256) {
        int r = l / 32, jt = l % 32;
        float h[8] = {0.f, 0.f, 0.f, 0.f, 0.f, 0.f, 0.f, 0.f};
        #pragma unroll
        for (int w = 0; w < 4; ++w) {
            float m  = packed[r][jt + w];
            int   ii = (int)(__float_as_uint(m) & 7u);
            #pragma unroll
            for (int o = 0; o < 8; ++o)
                h[o] += (ii == o) ? m : 0.0f;   // branchless, static index
        }
        #pragma unroll
        for (int o = 0; o < 8; ++o) hsum[o][r][jt] = h[o];
    }
    __syncthreads();

    // ---- phase 4: rolling vertical 4-row sum + coalesced store ----
    {
        const int o  = tid >> 5;    // 0..7  : channel
        const int jt = tid & 31;    // 0..31 : column
        const int j  = j0 + jt;
        float r0 = hsum[o][0][jt];
        float r1 = hsum[o][1][jt];
        float r2 = hsum[o][2][jt];
        #pragma unroll 4
        for (int it = 0; it < 32; ++it) {
            float r3 = hsum[o][it + 3][jt];
            float s  = (r0 + r1) + (r2 + r3);
            int i = i0 + it;
            if (i < NO && j < NO)
                out[((size_t)o * NO + i) * NO + j] = s;
            r0 = r1; r1 = r2; r2 = r3;
        }
    }
}

extern "C" void kernel_launch(void* const* d_in, const int* in_sizes, int n_in,
                              void* d_out, int out_size, void* d_ws, size_t ws_size,
                              hipStream_t stream) {
    const float* x = (const float*)d_in[0];
    float* out = (float*)d_out;

    // Emulate reference coefficient pipeline exactly:
    //   angle_o = f32( f32(2o+1) * f32(pi/8) ); coeff = f32(cos/sin(angle_o))
    OrientCoef cf;
    const float pi8 = (float)(M_PI / 8.0);   // fp32(pi/8)
    for (int o = 0; o < 8; ++o) {
        float angle = (float)(2 * o + 1) * pi8;          // f32 multiply
        cf.c[o] = (float)cos((double)angle);             // correctly-rounded f32
        cf.s[o] = (float)sin((double)angle);
    }

    dim3 grid(GW, GW);   // 129 x 129
    sift_fused<<<grid, dim3(256), 0, stream>>>(x, out, cf);
}

// Round 2
// 654.421 us; speedup vs baseline: 1.2367x; 1.0484x over previous
//
#include <hip/hip_runtime.h>
#include <math.h>

#define N   4096
#define NO  4097   // output spatial dim (4096 + 4pad - 4 + 1)
#define TO  32     // output tile
#define GW  129    // grid width = ceil(NO/TO)

struct OrientCoef { float c[8]; float s[8]; };

// LDS 10,664 B; 256 threads. 8 blocks/CU (wave-slot-limited) = 32 waves/CU.
__global__ __launch_bounds__(256, 8) void sift_fused(const float* __restrict__ x,
                                                     float* __restrict__ out,
                                                     OrientCoef cf) {
    // ---- bijective XCD-aware swizzle: consecutive tiles -> same XCD L2 ----
    int bid = blockIdx.y * GW + blockIdx.x;
    {
        const int nwg = GW * GW;             // 16641
        const int q = nwg / 8, r = nwg % 8;  // 2080, 1
        int xcd = bid & 7, local = bid >> 3;
        bid = (xcd < r ? xcd * (q + 1) : r * (q + 1) + (xcd - r) * q) + local;
    }
    const int i0  = (bid / GW) * TO;
    const int j0  = (bid % GW) * TO;
    const int tid = threadIdx.x;

    __shared__ float xs[37][38];       // input halo (+1 pad col)
    __shared__ float packed[35][36];   // (mag | idx) packed f32 (+1 pad col)

    // ---- phase 1: stage x halo (zero-padded) ----
    for (int l = tid; l < 37 * 37; l += 256) {
        int lr = l / 37, lc = l % 37;
        int gr = i0 - 3 + lr, gc = j0 - 3 + lc;
        float v = 0.0f;
        if (gr >= 0 && gr < N && gc >= 0 && gc < N) v = x[(size_t)gr * N + gc];
        xs[lr][lc] = v;
    }
    __syncthreads();

    // ---- phase 2: Sobel + magnitude + orientation argmax, pack (mag|idx) ----
    for (int l = tid; l < 35 * 35; l += 256) {
        int lr = l / 35, lc = l % 35;
        int gr = i0 - 2 + lr, gc = j0 - 2 + lc;
        float pv = 0.0f;
        if (gr >= 0 && gr < N && gc >= 0 && gc < N) {
            float x00 = xs[lr][lc],     x01 = xs[lr][lc + 1],     x02 = xs[lr][lc + 2];
            float x10 = xs[lr + 1][lc],                           x12 = xs[lr + 1][lc + 2];
            float x20 = xs[lr + 2][lc], x21 = xs[lr + 2][lc + 1], x22 = xs[lr + 2][lc + 2];
            // unflipped sobel taps (lax conv = cross-correlation)
            float dx = (x02 - x00) + 2.0f * (x12 - x10) + (x22 - x20);
            float dy = (x20 - x00) + 2.0f * (x21 - x01) + (x22 - x02);
            float mag = sqrtf(dx * dx + dy * dy);
            // per-bin coefficients (reference rounds each f32 angle separately)
            int best = 0;
            float bv = fmaf(cf.s[0], dy, cf.c[0] * dx);
            #pragma unroll
            for (int o = 1; o < 8; ++o) {
                float cs = fmaf(cf.s[o], dy, cf.c[o] * dx);
                if (cs > bv) { bv = cs; best = o; }
            }
            // pack idx into low 3 mantissa bits (<= 8e-7 relative mag error)
            pv = __uint_as_float((__float_as_uint(mag) & ~7u) | (unsigned)best);
        }
        packed[lr][lc] = pv;
    }
    __syncthreads();

    // ---- phase 3: per-(channel, column) rolling 4x4 box sum, direct store ----
    // thread -> (o, jt). Lanes sharing jt across o read identical LDS addrs
    // (broadcast, free); lanes across jt are stride-1 (conflict-free).
    {
        const int      o  = tid >> 5;          // 0..7  channel
        const int      jt = tid & 31;          // 0..31 column
        const int      j  = j0 + jt;
        const unsigned uo = (unsigned)o;
        const bool     jok = (j < NO);
        float* orow = out + ((size_t)o * NO + i0) * NO + j;
        float w0 = 0.f, w1 = 0.f, w2 = 0.f;    // rolling window h[r-3..r-1]
        #pragma unroll
        for (int r = 0; r < 35; ++r) {
            float m0 = packed[r][jt],     m1 = packed[r][jt + 1];
            float m2 = packed[r][jt + 2], m3 = packed[r][jt + 3];
            float h = 0.f;
            h += ((__float_as_uint(m0) & 7u) == uo) ? m0 : 0.f;
            h += ((__float_as_uint(m1) & 7u) == uo) ? m1 : 0.f;
            h += ((__float_as_uint(m2) & 7u) == uo) ? m2 : 0.f;
            h += ((__float_as_uint(m3) & 7u) == uo) ? m3 : 0.f;
            if (r >= 3) {                       // compile-time after unroll
                int i = i0 + r - 3;
                if (jok && i < NO)
                    orow[(size_t)(r - 3) * NO] = (w0 + w1) + (w2 + h);
            }
            w0 = w1; w1 = w2; w2 = h;
        }
    }
}

extern "C" void kernel_launch(void* const* d_in, const int* in_sizes, int n_in,
                              void* d_out, int out_size, void* d_ws, size_t ws_size,
                              hipStream_t stream) {
    const float* x = (const float*)d_in[0];
    float* out = (float*)d_out;

    // Emulate reference coefficient pipeline exactly:
    //   angle_o = f32( f32(2o+1) * f32(pi/8) ); coeff = f32(cos/sin(angle_o))
    OrientCoef cf;
    const float pi8 = (float)(M_PI / 8.0);   // fp32(pi/8)
    for (int o = 0; o < 8; ++o) {
        float angle = (float)(2 * o + 1) * pi8;          // f32 multiply
        cf.c[o] = (float)cos((double)angle);             // correctly-rounded f32
        cf.s[o] = (float)sin((double)angle);
    }

    dim3 grid(GW, GW);   // 129 x 129
    sift_fused<<<grid, dim3(256), 0, stream>>>(x, out, cf);
}